// Round 1
// 61.733 us; speedup vs baseline: 1.0107x; 1.0107x over previous
//
#include <hip/hip_runtime.h>

// WENO Black-Scholes time-stepper — register/DPP version.
// 81 grid points, 26 sequential Euler steps. One wave (64 lanes), 2 points
// per lane in registers (lane l holds u[2l], u[2l+1]).
//
// Change vs previous round: all __shfl_up/down(x,1) replaced with DPP
// wave_shr:1 / wave_shl:1 (__builtin_amdgcn_update_dpp). hipcc lowers generic
// __shfl to ds_bpermute_b32 (LDS pipe, ~30-120cy + lgkmcnt wait, 2 serialized
// stages per step); DPP is a single VALU-latency cross-lane mov. Arithmetic
// is kept bit-identical to the verified kernel (same ops, same order) so the
// numerical result is unchanged — only the shuffle mechanism differs.

#define MM 80
#define NSTEPS 26

// lane i <- lane i-1 (full-wave shift; lane 0 keeps its own value)
__device__ __forceinline__ float dpp_up1(float x) {
    return __int_as_float(__builtin_amdgcn_update_dpp(
        __float_as_int(x), __float_as_int(x), 0x138 /*wave_shr:1*/,
        0xf, 0xf, false));
}
// lane i <- lane i+1 (full-wave shift; lane 63 keeps its own value)
__device__ __forceinline__ float dpp_down1(float x) {
    return __int_as_float(__builtin_amdgcn_update_dpp(
        __float_as_int(x), __float_as_int(x), 0x130 /*wave_shl:1*/,
        0xf, 0xf, false));
}

__global__ __launch_bounds__(64)
void weno_bs_kernel(const float* __restrict__ om5,   // (80,3) fp32
                    const float* __restrict__ om6,   // (79,3) fp32
                    float* __restrict__ out)         // (81,)  fp32
{
    const float H      = 0.09375f;                    // (1.5-(-6))/80, exact
    const float INV_H  = 1.0f / 0.09375f;
    const float DT     = 1.0f / 26.0f;
    const float SIG2H2 = 0.045f / (0.09375f * 0.09375f);   // 0.5*sigma^2/H^2
    const float ADV    = 0.055f;                      // rate - 0.5*sigma^2
    const float RATE   = 0.1f;
    const float STRIKE = 50.0f;
    const float SIXTH  = 1.0f / 6.0f;

    const int l  = threadIdx.x;     // 0..63; lanes 0..40 carry real points
    const int p0 = 2 * l;           // even point index
    const int p1 = 2 * l + 1;       // odd point index

    // ---- per-lane weights (loaded once) ----
    // WENO5 flux weights: row i for uhat[i]  (i = p0, p1; valid i<80)
    float w5a0=0.f, w5a1=0.f, w5a2=0.f, w5b0=0.f, w5b1=0.f, w5b2=0.f;
    if (p0 < MM) { w5a0 = om5[3*p0+0]; w5a1 = om5[3*p0+1]; w5a2 = om5[3*p0+2]; }
    if (p1 < MM) { w5b0 = om5[3*p1+0]; w5b1 = om5[3*p1+1]; w5b2 = om5[3*p1+2]; }
    // 2nd-derivative weights: interior point p uses om6 row p-1 (rows 0..78)
    float w6a0=0.f, w6a1=0.f, w6a2=0.f, w6b0=0.f, w6b1=0.f, w6b2=0.f;
    if (p0 >= 1 && p0 <= MM-1) { int r = 3*(p0-1); w6a0=om6[r]; w6a1=om6[r+1]; w6a2=om6[r+2]; }
    if (p1 >= 1 && p1 <= MM-1) { int r = 3*(p1-1); w6b0=om6[r]; w6b1=om6[r+1]; w6b2=om6[r+2]; }

    // ---- initial condition: u = max(K*exp(x)-K, 0), x_p = -6 + p*H ----
    float u0 = 0.f, u1 = 0.f;
    if (p0 <= MM) u0 = fmaxf(STRIKE * expf(-6.0f + (float)p0 * H) - STRIKE, 0.0f);
    if (p1 <  MM) u1 = fmaxf(STRIKE * expf(-6.0f + (float)p1 * H) - STRIKE, 0.0f);

    const float s_right = STRIKE * expf(1.5f);
    const float F = expf(-RATE * DT);    // per-step discount factor
    float e = STRIKE;                    // e_n = K*exp(-r*t_n) via e *= F

    for (int s = 0; s < NSTEPS; ++s) {
        // neighbor windows: pm0=u[2l-2] pm1=u[2l-1] pp0=u[2l+2] pp1=u[2l+3]
        float pm0 = dpp_up1(u0);
        float pm1 = dpp_up1(u1);
        float pp0 = dpp_down1(u0);
        float pp1 = dpp_down1(u1);
        // ghosts: left u[-1]=u[-2]=u[0]; right u[81]=2*u[80]-u[79]
        if (l == 0)  { pm0 = u0; pm1 = u0; }
        if (l == 39) { pp1 = 2.0f * pp0 - u1; }   // pp0=u[80], u1=u[79]

        // WENO flux uhat[p0], uhat[p1]   (window u[i-2..i+2])
        float f0a = (2.0f*pm0 - 7.0f*pm1 + 11.0f*u0) * SIXTH;
        float f1a = (-pm1 + 5.0f*u0 + 2.0f*u1) * SIXTH;
        float f2a = (2.0f*u0 + 5.0f*u1 - pp0) * SIXTH;
        float uh0 = w5a0*f0a + w5a1*f1a + w5a2*f2a;

        float f0b = (2.0f*pm1 - 7.0f*u0 + 11.0f*u1) * SIXTH;
        float f1b = (-u0 + 5.0f*u1 + 2.0f*pp0) * SIXTH;
        float f2b = (2.0f*u1 + 5.0f*pp0 - pp1) * SIXTH;
        float uh1 = w5b0*f0b + w5b1*f1b + w5b2*f2b;

        // central 2nd-derivative combos (shared sub-expressions)
        float c0a = pm0 - 2.0f*pm1 + u0;
        float c1a = pm1 - 2.0f*u0  + u1;   // == c0 for point p1
        float c2a = u0  - 2.0f*u1  + pp0;  // == c1 for point p1
        float c2b = u1  - 2.0f*pp0 + pp1;
        float uxx0 = w6a0*c0a + w6a1*c1a + w6a2*c2a;
        float uxx1 = w6b0*c1a + w6b1*c2a + w6b2*c2b;

        // uhat[p0-1] lives in lane l-1's uh1
        float uhm = dpp_up1(uh1);

        float nu0 = u0 + DT*(SIG2H2*uxx0 + ADV*((uh0 - uhm)*INV_H) - RATE*u0);
        float nu1 = u1 + DT*(SIG2H2*uxx1 + ADV*((uh1 - uh0)*INV_H) - RATE*u1);

        e *= F;
        // interior updates: even points 2..78 (lanes 1..39), odd 1..79 (0..39)
        if (l >= 1 && l <= 39) u0 = nu0;
        if (l <= 39)           u1 = nu1;
        if (l == 40)           u0 = s_right - e;   // right BC at t_{n+1}
        // lane 0: u0 stays 0 (left BC)
    }

    if (p0 <= MM) out[p0] = u0;
    if (p1 <= MM) out[p1] = u1;
}

extern "C" void kernel_launch(void* const* d_in, const int* in_sizes, int n_in,
                              void* d_out, int out_size, void* d_ws, size_t ws_size,
                              hipStream_t stream) {
    const float* om5 = (const float*)d_in[0];
    const float* om6 = (const float*)d_in[1];
    float* out = (float*)d_out;
    weno_bs_kernel<<<dim3(1), dim3(64), 0, stream>>>(om5, om6, out);
}